// Round 3
// baseline (19389.261 us; speedup 1.0000x reference)
//
#include <hip/hip_runtime.h>
#include <math.h>

typedef _Float16 f16;
typedef _Float16 f16x8 __attribute__((ext_vector_type(8)));
typedef float f32x4 __attribute__((ext_vector_type(4)));

#define NWG 160
#define NT 40  // 40 column groups x 32 cols (32 h-groups, 8 y-groups)
#define MT 4   // 4 row groups x 64 rows

// ---------------- prep kernels ----------------

// traj[0] = x0 (fp32), x0 split into hi/lo f16; block 0 also resets sync counter
__global__ __launch_bounds__(256) void prep_copy_x0(const float* __restrict__ x0,
                                                    float* __restrict__ traj,
                                                    f16* __restrict__ xhi,
                                                    f16* __restrict__ xlo,
                                                    unsigned* __restrict__ sync) {
    if (blockIdx.x == 0 && threadIdx.x == 0) *sync = 0u;
    int i = blockIdx.x * 256 + threadIdx.x;  // 65536 total
    float v = x0[i];
    traj[i] = v;
    f16 h = (f16)v;
    xhi[i] = h;
    xlo[i] = (f16)(v - (float)h);
}

__global__ __launch_bounds__(256) void prep_cast2(const float* __restrict__ src,
                                                  f16* __restrict__ hi,
                                                  f16* __restrict__ lo) {
    int i = blockIdx.x * 256 + threadIdx.x;
    float v = src[i];
    f16 h = (f16)v;
    hi[i] = h;
    lo[i] = (f16)(v - (float)h);
}

__global__ __launch_bounds__(256) void prep_bias(const float* __restrict__ bih,
                                                 const float* __restrict__ bhh,
                                                 const float* __restrict__ bfc,
                                                 const float* __restrict__ Wih,
                                                 float* __restrict__ b1,
                                                 float* __restrict__ bcmb) {
    int wave = blockIdx.x * 4 + (threadIdx.x >> 6);  // 64 waves total
    int lane = threadIdx.x & 63;
    for (int j = wave * 16; j < wave * 16 + 16; ++j) {
        float s = 0.f;
        for (int o = lane; o < 256; o += 64) s += bfc[o] * Wih[j * 256 + o];
        for (int off = 32; off; off >>= 1) s += __shfl_down(s, off);
        if (lane == 0) {
            float t = bih[j] + bhh[j];
            b1[j] = t;
            bcmb[j] = t + s;
        }
    }
}

// Bt[j][k] = W_hh[j][k] + sum_o W_ih[j][o] * W_fc[o][k]  (fp32), split hi/lo
__global__ __launch_bounds__(256) void prep_wcmb(const float* __restrict__ Wih,
                                                 const float* __restrict__ Wfc,
                                                 const float* __restrict__ Whh,
                                                 f16* __restrict__ Bt_hi,
                                                 f16* __restrict__ Bt_lo) {
    __shared__ float As[64][65];
    __shared__ float Bs[64][65];
    int j0 = blockIdx.y * 64, k0 = blockIdx.x * 64;
    int tid = threadIdx.x;
    float acc[4][4] = {};
    for (int o0 = 0; o0 < 256; o0 += 64) {
        __syncthreads();
        #pragma unroll
        for (int i = 0; i < 16; ++i) {
            int e = i * 256 + tid;
            int r = e >> 6, c = e & 63;
            As[r][c] = Wih[(j0 + r) * 256 + o0 + c];
            Bs[r][c] = Wfc[(o0 + r) * 1024 + k0 + c];
        }
        __syncthreads();
        int ty = tid >> 4, tx = tid & 15;
        for (int o = 0; o < 64; ++o) {
            float a[4], b[4];
            #pragma unroll
            for (int i = 0; i < 4; ++i) a[i] = As[ty * 4 + i][o];
            #pragma unroll
            for (int i = 0; i < 4; ++i) b[i] = Bs[o][tx * 4 + i];
            #pragma unroll
            for (int i = 0; i < 4; ++i)
                #pragma unroll
                for (int jj = 0; jj < 4; ++jj) acc[i][jj] += a[i] * b[jj];
        }
    }
    int ty = tid >> 4, tx = tid & 15;
    #pragma unroll
    for (int i = 0; i < 4; ++i)
        #pragma unroll
        for (int jj = 0; jj < 4; ++jj) {
            int j = j0 + ty * 4 + i, k = k0 + tx * 4 + jj;
            float v = acc[i][jj] + Whh[j * 1024 + k];
            f16 h = (f16)v;
            Bt_hi[j * 1024 + k] = h;
            Bt_lo[j * 1024 + k] = (f16)(v - (float)h);
        }
}

// ---------------- persistent rollout kernel ----------------

__device__ __forceinline__ void grid_barrier(unsigned* cnt, unsigned target) {
    __syncthreads();
    if (threadIdx.x == 0) {
        __threadfence();  // agent-scope: flush this XCD's dirty L2 (h writes) to L3
        __hip_atomic_fetch_add(cnt, 1u, __ATOMIC_RELEASE, __HIP_MEMORY_SCOPE_AGENT);
        while (__hip_atomic_load(cnt, __ATOMIC_ACQUIRE, __HIP_MEMORY_SCOPE_AGENT) < target)
            __builtin_amdgcn_s_sleep(1);
    }
    __syncthreads();
}

// K=1024 tile GEMM: B_hi from swizzled LDS, B_lo + A(hi/lo) from global.
// Kept __forceinline__ so the LDS address-space provenance survives.
__device__ __forceinline__ f32x4 gemm_k1024(const f16* __restrict__ a_h,
                                            const f16* __restrict__ a_l,
                                            const f16* __restrict__ b_l,
                                            const char* bs_base, int cl, int klo) {
    f32x4 acc = {0.f, 0.f, 0.f, 0.f};
    #pragma unroll 4
    for (int kk = 0; kk < 1024; kk += 32) {
        f16x8 ah = *(const f16x8*)(a_h + kk);
        f16x8 al = *(const f16x8*)(a_l + kk);
        int bo = cl * 2048 + (klo + kk) * 2;
        f16x8 bh = *(const f16x8*)(bs_base + (bo ^ ((cl & 7) << 4)));
        f16x8 bl = *(const f16x8*)(b_l + kk);
        acc = __builtin_amdgcn_mfma_f32_16x16x32_f16(ah, bh, acc, 0, 0, 0);
        acc = __builtin_amdgcn_mfma_f32_16x16x32_f16(ah, bl, acc, 0, 0, 0);
        acc = __builtin_amdgcn_mfma_f32_16x16x32_f16(al, bh, acc, 0, 0, 0);
    }
    return acc;
}

__global__ __launch_bounds__(512, 1) void rollout(
    const f16* __restrict__ x0_hi, const f16* __restrict__ x0_lo,
    const f16* __restrict__ Wih_hi, const f16* __restrict__ Wih_lo,
    const f16* __restrict__ Bt_hi, const f16* __restrict__ Bt_lo,
    const float* __restrict__ b1, const float* __restrict__ bcmb,
    const float* __restrict__ bfc,
    f16* __restrict__ h_hi0, f16* __restrict__ h_lo0,
    f16* __restrict__ h_hi1, f16* __restrict__ h_lo1,
    float* __restrict__ traj, unsigned* __restrict__ sync) {
    __shared__ f16 Bs[32 * 1024];  // 64 KB: B_hi slice, swizzled

    int wg = blockIdx.x;
    int nt = wg % NT;  // column group (0..39)
    int mt = wg / NT;  // row group (0..3)
    int tid = threadIdx.x;
    int lane = tid & 63;
    int wid = tid >> 6;   // 0..7
    int mf = wid >> 1;    // 0..3: M fragment
    int nf = wid & 1;     // 0..1: N fragment
    int l15 = lane & 15;
    int klo = (lane >> 4) * 8;

    int arow = mt * 64 + mf * 16 + l15;   // A row this lane reads
    int colg = nt * 32 + nf * 16 + l15;   // global output column (0..1279)
    int cl = nf * 16 + l15;               // local column in LDS slice
    bool is_h = (nt < 32);
    int orow = mt * 64 + mf * 16 + (lane >> 4) * 4;  // output row base (D frag)

    // ---- pin B_hi slice in LDS (once) ----
    {
        const char* gsrc = (const char*)(Bt_hi + (size_t)nt * 32 * 1024);
        char* bs = (char*)Bs;
        #pragma unroll
        for (int i = 0; i < 8; ++i) {
            int f = (tid + i * 512) * 16;  // byte offset within 64 KB slice
            int c = f >> 11;               // column = f / 2048
            f16x8 v = *(const f16x8*)(gsrc + f);
            *(f16x8*)(bs + (f ^ ((c & 7) << 4))) = v;
        }
    }

    float bias_c = is_h ? bcmb[colg] : bfc[colg - 1024];

    // ---- step 1: h_1 = tanh(x0 @ Wih^T + b_ih + b_hh) -> buf1 (h-WGs only) ----
    if (is_h) {
        float bias1_c = b1[colg];
        const f16* a_h = x0_hi + arow * 256 + klo;
        const f16* a_l = x0_lo + arow * 256 + klo;
        const f16* b_h = Wih_hi + colg * 256 + klo;
        const f16* b_lp = Wih_lo + colg * 256 + klo;
        f32x4 acc = {0.f, 0.f, 0.f, 0.f};
        #pragma unroll
        for (int kk = 0; kk < 256; kk += 32) {
            f16x8 ah = *(const f16x8*)(a_h + kk);
            f16x8 al = *(const f16x8*)(a_l + kk);
            f16x8 bh = *(const f16x8*)(b_h + kk);
            f16x8 bl = *(const f16x8*)(b_lp + kk);
            acc = __builtin_amdgcn_mfma_f32_16x16x32_f16(ah, bh, acc, 0, 0, 0);
            acc = __builtin_amdgcn_mfma_f32_16x16x32_f16(ah, bl, acc, 0, 0, 0);
            acc = __builtin_amdgcn_mfma_f32_16x16x32_f16(al, bh, acc, 0, 0, 0);
        }
        #pragma unroll
        for (int r = 0; r < 4; ++r) {
            float t = tanhf(acc[r] + bias1_c);
            f16 th = (f16)t;
            h_hi1[(orow + r) * 1024 + colg] = th;
            h_lo1[(orow + r) * 1024 + colg] = (f16)(t - (float)th);
        }
    }
    grid_barrier(sync, 1u * NWG);

    // ---- main loop: iteration t computes h_t (h-WGs) and y_{t-1} (y-WGs) ----
    const char* bs_base = (const char*)Bs;
    const f16* b_l = Bt_lo + (size_t)colg * 1024 + klo;
    for (int t = 2; t <= 511; ++t) {
        int src = (t - 1) & 1;
        const f16* a_h = (src ? h_hi1 : h_hi0) + arow * 1024 + klo;
        const f16* a_l = (src ? h_lo1 : h_lo0) + arow * 1024 + klo;
        f32x4 acc = gemm_k1024(a_h, a_l, b_l, bs_base, cl, klo);
        if (is_h) {
            f16* dh = (t & 1) ? h_hi1 : h_hi0;
            f16* dl = (t & 1) ? h_lo1 : h_lo0;
            #pragma unroll
            for (int r = 0; r < 4; ++r) {
                float v = tanhf(acc[r] + bias_c);
                f16 th = (f16)v;
                dh[(orow + r) * 1024 + colg] = th;
                dl[(orow + r) * 1024 + colg] = (f16)(v - (float)th);
            }
        } else {
            float* y = traj + (size_t)(t - 1) * 65536;
            #pragma unroll
            for (int r = 0; r < 4; ++r)
                y[(orow + r) * 256 + (colg - 1024)] = acc[r] + bias_c;
        }
        grid_barrier(sync, (unsigned)t * NWG);
    }

    // ---- final: y_511 from h_511 (buf1) ----
    if (!is_h) {
        const f16* a_h = h_hi1 + arow * 1024 + klo;
        const f16* a_l = h_lo1 + arow * 1024 + klo;
        f32x4 acc = gemm_k1024(a_h, a_l, b_l, bs_base, cl, klo);
        float* y = traj + (size_t)511 * 65536;
        #pragma unroll
        for (int r = 0; r < 4; ++r)
            y[(orow + r) * 256 + (colg - 1024)] = acc[r] + bias_c;
    }
}

// ---------------- launch ----------------

extern "C" void kernel_launch(void* const* d_in, const int* in_sizes, int n_in,
                              void* d_out, int out_size, void* d_ws, size_t ws_size,
                              hipStream_t stream) {
    const float* x0 = (const float*)d_in[0];
    const float* Wih = (const float*)d_in[1];
    const float* bih = (const float*)d_in[2];
    const float* Whh = (const float*)d_in[3];
    const float* bhh = (const float*)d_in[4];
    const float* Wfc = (const float*)d_in[5];
    const float* bfc = (const float*)d_in[6];
    float* traj = (float*)d_out;  // [512][256][256]

    char* w = (char*)d_ws;
    size_t off = 0;
    f16* Bt_hi = (f16*)(w + off); off += 1280u * 1024 * 2;   // 2,621,440
    f16* Bt_lo = (f16*)(w + off); off += 1280u * 1024 * 2;
    f16* Wih_hi = (f16*)(w + off); off += 1024u * 256 * 2;
    f16* Wih_lo = (f16*)(w + off); off += 1024u * 256 * 2;
    f16* x0_hi = (f16*)(w + off); off += 256u * 256 * 2;
    f16* x0_lo = (f16*)(w + off); off += 256u * 256 * 2;
    f16* h_hi0 = (f16*)(w + off); off += 256u * 1024 * 2;
    f16* h_lo0 = (f16*)(w + off); off += 256u * 1024 * 2;
    f16* h_hi1 = (f16*)(w + off); off += 256u * 1024 * 2;
    f16* h_lo1 = (f16*)(w + off); off += 256u * 1024 * 2;
    float* b1 = (float*)(w + off); off += 4096;
    float* bcmb = (float*)(w + off); off += 4096;
    unsigned* sync = (unsigned*)(w + off); off += 4096;

    // prep (also resets sync counter every launch -> graph-replay safe)
    prep_copy_x0<<<dim3(256), dim3(256), 0, stream>>>(x0, traj, x0_hi, x0_lo, sync);
    prep_cast2<<<dim3(1024), dim3(256), 0, stream>>>(Wih, Wih_hi, Wih_lo);
    prep_bias<<<dim3(16), dim3(256), 0, stream>>>(bih, bhh, bfc, Wih, b1, bcmb);
    prep_cast2<<<dim3(1024), dim3(256), 0, stream>>>(Wfc, Bt_hi + 1024 * 1024,
                                                     Bt_lo + 1024 * 1024);
    prep_wcmb<<<dim3(16, 16), dim3(256), 0, stream>>>(Wih, Wfc, Whh, Bt_hi, Bt_lo);

    // persistent rollout: 160 WGs (1 per CU; 64 KB LDS) x 512 threads
    rollout<<<dim3(NWG), dim3(512), 0, stream>>>(
        x0_hi, x0_lo, Wih_hi, Wih_lo, Bt_hi, Bt_lo, b1, bcmb, bfc,
        h_hi0, h_lo0, h_hi1, h_lo1, traj, sync);
}

// Round 4
// 11341.374 us; speedup vs baseline: 1.7096x; 1.7096x over previous
//
#include <hip/hip_runtime.h>
#include <math.h>

typedef _Float16 f16;
typedef _Float16 f16x8 __attribute__((ext_vector_type(8)));
typedef float f32x4 __attribute__((ext_vector_type(4)));

#define NWG 160
#define CG 20  // col groups per row group (16 h + 4 y)

// ---------------- prep kernels ----------------

// traj[0] = x0 (fp32), x0 split into hi/lo f16; block 0 zeroes the sync area
__global__ __launch_bounds__(256) void prep_copy_x0(const float* __restrict__ x0,
                                                    float* __restrict__ traj,
                                                    f16* __restrict__ xhi,
                                                    f16* __restrict__ xlo,
                                                    unsigned* __restrict__ syncarea) {
    if (blockIdx.x == 0) {
        #pragma unroll
        for (int j = 0; j < 4; ++j) syncarea[threadIdx.x * 4 + j] = 0u;
    }
    int i = blockIdx.x * 256 + threadIdx.x;  // 65536 total
    float v = x0[i];
    traj[i] = v;
    f16 h = (f16)v;
    xhi[i] = h;
    xlo[i] = (f16)(v - (float)h);
}

__global__ __launch_bounds__(256) void prep_cast2(const float* __restrict__ src,
                                                  f16* __restrict__ hi,
                                                  f16* __restrict__ lo) {
    int i = blockIdx.x * 256 + threadIdx.x;
    float v = src[i];
    f16 h = (f16)v;
    hi[i] = h;
    lo[i] = (f16)(v - (float)h);
}

__global__ __launch_bounds__(256) void prep_bias(const float* __restrict__ bih,
                                                 const float* __restrict__ bhh,
                                                 const float* __restrict__ bfc,
                                                 const float* __restrict__ Wih,
                                                 float* __restrict__ b1,
                                                 float* __restrict__ bcmb) {
    int wave = blockIdx.x * 4 + (threadIdx.x >> 6);  // 64 waves total
    int lane = threadIdx.x & 63;
    for (int j = wave * 16; j < wave * 16 + 16; ++j) {
        float s = 0.f;
        for (int o = lane; o < 256; o += 64) s += bfc[o] * Wih[j * 256 + o];
        for (int off = 32; off; off >>= 1) s += __shfl_down(s, off);
        if (lane == 0) {
            float t = bih[j] + bhh[j];
            b1[j] = t;
            bcmb[j] = t + s;
        }
    }
}

// Bt[j][k] = W_hh[j][k] + sum_o W_ih[j][o] * W_fc[o][k]  (fp32), split hi/lo
__global__ __launch_bounds__(256) void prep_wcmb(const float* __restrict__ Wih,
                                                 const float* __restrict__ Wfc,
                                                 const float* __restrict__ Whh,
                                                 f16* __restrict__ Bt_hi,
                                                 f16* __restrict__ Bt_lo) {
    __shared__ float As[64][65];
    __shared__ float Bs[64][65];
    int j0 = blockIdx.y * 64, k0 = blockIdx.x * 64;
    int tid = threadIdx.x;
    float acc[4][4] = {};
    for (int o0 = 0; o0 < 256; o0 += 64) {
        __syncthreads();
        #pragma unroll
        for (int i = 0; i < 16; ++i) {
            int e = i * 256 + tid;
            int r = e >> 6, c = e & 63;
            As[r][c] = Wih[(j0 + r) * 256 + o0 + c];
            Bs[r][c] = Wfc[(o0 + r) * 1024 + k0 + c];
        }
        __syncthreads();
        int ty = tid >> 4, tx = tid & 15;
        for (int o = 0; o < 64; ++o) {
            float a[4], b[4];
            #pragma unroll
            for (int i = 0; i < 4; ++i) a[i] = As[ty * 4 + i][o];
            #pragma unroll
            for (int i = 0; i < 4; ++i) b[i] = Bs[o][tx * 4 + i];
            #pragma unroll
            for (int i = 0; i < 4; ++i)
                #pragma unroll
                for (int jj = 0; jj < 4; ++jj) acc[i][jj] += a[i] * b[jj];
        }
    }
    int ty = tid >> 4, tx = tid & 15;
    #pragma unroll
    for (int i = 0; i < 4; ++i)
        #pragma unroll
        for (int jj = 0; jj < 4; ++jj) {
            int j = j0 + ty * 4 + i, k = k0 + tx * 4 + jj;
            float v = acc[i][jj] + Whh[j * 1024 + k];
            f16 h = (f16)v;
            Bt_hi[j * 1024 + k] = h;
            Bt_lo[j * 1024 + k] = (f16)(v - (float)h);
        }
}

// ---------------- persistent rollout kernel ----------------

// Per-row-group barrier. fast = all 20 members on one XCD (shared L2):
//   relaxed arrive, relaxed spin, L1-only buffer_inv (L2 is coherence point).
// slow = cross-XCD: release fence (wbl2) before arrive, acquire fence (inv) after.
__device__ __forceinline__ void group_barrier(unsigned* cnt, unsigned target, bool fast) {
    __syncthreads();  // drains vmcnt: all threads' h stores committed to L2
    if (threadIdx.x == 0) {
        if (!fast) __builtin_amdgcn_fence(__ATOMIC_RELEASE, "agent");
        __hip_atomic_fetch_add(cnt, 1u, __ATOMIC_RELAXED, __HIP_MEMORY_SCOPE_AGENT);
        while (__hip_atomic_load(cnt, __ATOMIC_RELAXED, __HIP_MEMORY_SCOPE_AGENT) < target)
            __builtin_amdgcn_s_sleep(1);
        if (fast) {
            asm volatile("s_waitcnt vmcnt(0)\n\tbuffer_inv" ::: "memory");
        } else {
            __builtin_amdgcn_fence(__ATOMIC_ACQUIRE, "agent");
        }
    }
    __syncthreads();
}

__global__ __launch_bounds__(512, 1) void rollout(
    const f16* __restrict__ x0_hi, const f16* __restrict__ x0_lo,
    const f16* __restrict__ Wih_hi, const f16* __restrict__ Wih_lo,
    const f16* __restrict__ Bt_hi, const f16* __restrict__ Bt_lo,
    const float* __restrict__ b1, const float* __restrict__ bcmb,
    const float* __restrict__ bfc,
    f16* __restrict__ h_hi0, f16* __restrict__ h_lo0,
    f16* __restrict__ h_hi1, f16* __restrict__ h_lo1,
    float* __restrict__ traj, unsigned* __restrict__ syncarea,
    unsigned* __restrict__ xcc_arr) {
    __shared__ f16 Bs[64 * 1024];  // 128 KB: B_hi slice (64 cols x K=1024), swizzled
    __shared__ unsigned s_fast;

    int wg = blockIdx.x;
    int g = wg & 7;    // row group: rows g*32 .. g*32+31 (one XCD under %8 round-robin)
    int cg = wg >> 3;  // col group 0..19 (0..15 h, 16..19 y)
    int tid = threadIdx.x;
    int lane = tid & 63;
    int wid = tid >> 6;   // 0..7
    int mf = wid & 1;     // M fragment (2 x 16 rows)
    int nf = wid >> 1;    // N fragment (4 x 16 cols)
    int l15 = lane & 15;
    int klo = (lane >> 4) * 8;

    bool is_h = (cg < 16);
    int colbase = is_h ? cg * 64 : 1024 + (cg - 16) * 64;
    int cl = nf * 16 + l15;        // local col 0..63
    int colg = colbase + cl;       // global col in Bt (0..1279)
    int arow = g * 32 + mf * 16 + l15;
    int orow = g * 32 + mf * 16 + (lane >> 4) * 4;

    unsigned* cnt = syncarea + g * 64;      // 256B-spaced per-group counters
    unsigned* initcnt = syncarea + 512;

    // ---- stage B_hi slice to LDS (XOR-swizzled) ----
    {
        const char* gsrc = (const char*)(Bt_hi + (size_t)colbase * 1024);
        char* bs = (char*)Bs;
        #pragma unroll
        for (int i = 0; i < 16; ++i) {
            int f = (tid + i * 512) * 16;  // 0 .. 131072
            int c = f >> 11;
            f16x8 v = *(const f16x8*)(gsrc + f);
            *(f16x8*)(bs + (f ^ ((c & 7) << 4))) = v;
        }
    }

    // ---- XCD detection + init barrier (always full agent scope) ----
    if (tid == 0) {
        unsigned xcc;
        asm volatile("s_getreg_b32 %0, hwreg(HW_REG_XCC_ID)" : "=s"(xcc));
        __hip_atomic_store(&xcc_arr[wg], xcc, __ATOMIC_RELAXED, __HIP_MEMORY_SCOPE_AGENT);
        __hip_atomic_fetch_add(initcnt, 1u, __ATOMIC_RELEASE, __HIP_MEMORY_SCOPE_AGENT);
        while (__hip_atomic_load(initcnt, __ATOMIC_RELAXED, __HIP_MEMORY_SCOPE_AGENT) < NWG)
            __builtin_amdgcn_s_sleep(1);
        __builtin_amdgcn_fence(__ATOMIC_ACQUIRE, "agent");
        unsigned f = 1;
        for (int i = 0; i < CG; ++i) {
            unsigned o = __hip_atomic_load(&xcc_arr[g + i * 8], __ATOMIC_RELAXED,
                                           __HIP_MEMORY_SCOPE_AGENT);
            if (o != xcc) f = 0;
        }
        s_fast = f;
    }
    __syncthreads();
    bool fast = (s_fast != 0);

    // ---- step 1: h_1 = tanh(x0 @ Wih^T + b_ih + b_hh) -> buf1 (h-WGs only) ----
    if (is_h) {
        const f16* a_h = x0_hi + arow * 256 + klo;
        const f16* a_l = x0_lo + arow * 256 + klo;
        const f16* b_h = Wih_hi + (size_t)colg * 256 + klo;
        const f16* b_lp = Wih_lo + (size_t)colg * 256 + klo;
        f32x4 acc = {0.f, 0.f, 0.f, 0.f};
        #pragma unroll
        for (int kk = 0; kk < 256; kk += 32) {
            f16x8 ah = *(const f16x8*)(a_h + kk);
            f16x8 al = *(const f16x8*)(a_l + kk);
            f16x8 bh = *(const f16x8*)(b_h + kk);
            f16x8 bl = *(const f16x8*)(b_lp + kk);
            acc = __builtin_amdgcn_mfma_f32_16x16x32_f16(ah, bh, acc, 0, 0, 0);
            acc = __builtin_amdgcn_mfma_f32_16x16x32_f16(ah, bl, acc, 0, 0, 0);
            acc = __builtin_amdgcn_mfma_f32_16x16x32_f16(al, bh, acc, 0, 0, 0);
        }
        float bias1 = b1[colg];
        #pragma unroll
        for (int r = 0; r < 4; ++r) {
            float t = tanhf(acc[r] + bias1);
            f16 th = (f16)t;
            h_hi1[(orow + r) * 1024 + colg] = th;
            h_lo1[(orow + r) * 1024 + colg] = (f16)(t - (float)th);
        }
    }
    group_barrier(cnt, CG, fast);

    // ---- main loop: iteration t computes h_t (h-WGs) and y_{t-1} (y-WGs) ----
    const char* bs = (const char*)Bs;
    const f16* b_l_base = Bt_lo + (size_t)colg * 1024 + klo;
    float bias_c = is_h ? bcmb[colg] : bfc[colg - 1024];
    int swz = (cl & 7) << 4;
    int bo0 = cl * 2048 + klo * 2;

    for (int t = 2; t <= 511; ++t) {
        const f16* src_h = ((t - 1) & 1) ? h_hi1 : h_hi0;
        const f16* src_l = ((t - 1) & 1) ? h_lo1 : h_lo0;
        const f16* a_h = src_h + (size_t)arow * 1024 + klo;
        const f16* a_l = src_l + (size_t)arow * 1024 + klo;
        f32x4 acc = {0.f, 0.f, 0.f, 0.f};
        #pragma unroll 4
        for (int kk = 0; kk < 1024; kk += 32) {
            f16x8 ah = *(const f16x8*)(a_h + kk);
            f16x8 al = *(const f16x8*)(a_l + kk);
            f16x8 bh = *(const f16x8*)(bs + ((bo0 + kk * 2) ^ swz));
            f16x8 bl = *(const f16x8*)(b_l_base + kk);
            acc = __builtin_amdgcn_mfma_f32_16x16x32_f16(ah, bh, acc, 0, 0, 0);
            acc = __builtin_amdgcn_mfma_f32_16x16x32_f16(ah, bl, acc, 0, 0, 0);
            acc = __builtin_amdgcn_mfma_f32_16x16x32_f16(al, bh, acc, 0, 0, 0);
        }
        if (is_h) {
            f16* dh = (t & 1) ? h_hi1 : h_hi0;
            f16* dl = (t & 1) ? h_lo1 : h_lo0;
            #pragma unroll
            for (int r = 0; r < 4; ++r) {
                float v = tanhf(acc[r] + bias_c);
                f16 th = (f16)v;
                dh[(orow + r) * 1024 + colg] = th;
                dl[(orow + r) * 1024 + colg] = (f16)(v - (float)th);
            }
        } else {
            float* y = traj + (size_t)(t - 1) * 65536;
            #pragma unroll
            for (int r = 0; r < 4; ++r)
                y[(orow + r) * 256 + (colg - 1024)] = acc[r] + bias_c;
        }
        group_barrier(cnt, (unsigned)t * CG, fast);
    }

    // ---- final: y_511 from h_511 (buf1) ----
    if (!is_h) {
        const f16* a_h = h_hi1 + (size_t)arow * 1024 + klo;
        const f16* a_l = h_lo1 + (size_t)arow * 1024 + klo;
        f32x4 acc = {0.f, 0.f, 0.f, 0.f};
        #pragma unroll 4
        for (int kk = 0; kk < 1024; kk += 32) {
            f16x8 ah = *(const f16x8*)(a_h + kk);
            f16x8 al = *(const f16x8*)(a_l + kk);
            f16x8 bh = *(const f16x8*)(bs + ((bo0 + kk * 2) ^ swz));
            f16x8 bl = *(const f16x8*)(b_l_base + kk);
            acc = __builtin_amdgcn_mfma_f32_16x16x32_f16(ah, bh, acc, 0, 0, 0);
            acc = __builtin_amdgcn_mfma_f32_16x16x32_f16(ah, bl, acc, 0, 0, 0);
            acc = __builtin_amdgcn_mfma_f32_16x16x32_f16(al, bh, acc, 0, 0, 0);
        }
        float* y = traj + (size_t)511 * 65536;
        #pragma unroll
        for (int r = 0; r < 4; ++r)
            y[(orow + r) * 256 + (colg - 1024)] = acc[r] + bias_c;
    }
}

// ---------------- launch ----------------

extern "C" void kernel_launch(void* const* d_in, const int* in_sizes, int n_in,
                              void* d_out, int out_size, void* d_ws, size_t ws_size,
                              hipStream_t stream) {
    const float* x0 = (const float*)d_in[0];
    const float* Wih = (const float*)d_in[1];
    const float* bih = (const float*)d_in[2];
    const float* Whh = (const float*)d_in[3];
    const float* bhh = (const float*)d_in[4];
    const float* Wfc = (const float*)d_in[5];
    const float* bfc = (const float*)d_in[6];
    float* traj = (float*)d_out;  // [512][256][256]

    char* w = (char*)d_ws;
    size_t off = 0;
    f16* Bt_hi = (f16*)(w + off); off += 1280u * 1024 * 2;
    f16* Bt_lo = (f16*)(w + off); off += 1280u * 1024 * 2;
    f16* Wih_hi = (f16*)(w + off); off += 1024u * 256 * 2;
    f16* Wih_lo = (f16*)(w + off); off += 1024u * 256 * 2;
    f16* x0_hi = (f16*)(w + off); off += 256u * 256 * 2;
    f16* x0_lo = (f16*)(w + off); off += 256u * 256 * 2;
    f16* h_hi0 = (f16*)(w + off); off += 256u * 1024 * 2;
    f16* h_lo0 = (f16*)(w + off); off += 256u * 1024 * 2;
    f16* h_hi1 = (f16*)(w + off); off += 256u * 1024 * 2;
    f16* h_lo1 = (f16*)(w + off); off += 256u * 1024 * 2;
    float* b1 = (float*)(w + off); off += 4096;
    float* bcmb = (float*)(w + off); off += 4096;
    unsigned* syncarea = (unsigned*)(w + off); off += 4096;  // counters + initcnt
    unsigned* xcc_arr = (unsigned*)(w + off); off += 1024;

    // prep (zeroes sync area every launch -> graph-replay safe)
    prep_copy_x0<<<dim3(256), dim3(256), 0, stream>>>(x0, traj, x0_hi, x0_lo, syncarea);
    prep_cast2<<<dim3(1024), dim3(256), 0, stream>>>(Wih, Wih_hi, Wih_lo);
    prep_bias<<<dim3(16), dim3(256), 0, stream>>>(bih, bhh, bfc, Wih, b1, bcmb);
    prep_cast2<<<dim3(1024), dim3(256), 0, stream>>>(Wfc, Bt_hi + 1024 * 1024,
                                                     Bt_lo + 1024 * 1024);
    prep_wcmb<<<dim3(16, 16), dim3(256), 0, stream>>>(Wih, Wfc, Whh, Bt_hi, Bt_lo);

    // persistent rollout: 160 WGs x 512 threads, 1 WG/CU (128 KB LDS)
    rollout<<<dim3(NWG), dim3(512), 0, stream>>>(
        x0_hi, x0_lo, Wih_hi, Wih_lo, Bt_hi, Bt_lo, b1, bcmb, bfc,
        h_hi0, h_lo0, h_hi1, h_lo1, traj, syncarea, xcc_arr);
}